// Round 4
// baseline (886.024 us; speedup 1.0000x reference)
//
#include <hip/hip_runtime.h>

#define IN_HW 512
#define OUT_HW 1024
#define NB 32
#define NC 3
#define TOH 32
#define TOW 128
#define NTHREADS 256

// ---------------- sortable-key encoding for f32 atomics ----------------------
__device__ __forceinline__ unsigned enc_f(float f) {
  unsigned u = __float_as_uint(f);
  return (u & 0x80000000u) ? ~u : (u | 0x80000000u);
}
__device__ __forceinline__ float dec_f(unsigned k) {
  unsigned u = (k & 0x80000000u) ? (k ^ 0x80000000u) : ~k;
  return __uint_as_float(u);
}

// ---------------- hardcoded normalized Lanczos4 2x-upsample weights ----------
// Derived in f64: w(d)=sinc(d)sinc(d/4), phases d=3.75-j (even) / 3.25-j (odd),
// normalized to sum 1. Max abs error ~2e-6 -> output perturbation ~0.05 u8
// levels; cannot change absmax class.
#define LW_A -0.00397053f  /* |d|=3.75 */
#define LW_B  0.03146474f  /* |d|=2.75 */
#define LW_C -0.09165979f  /* |d|=1.75 */
#define LW_D  0.28268104f  /* |d|=0.75 */
#define LW_E  0.89337959f  /* |d|=0.25 */
#define LW_F -0.15228947f  /* |d|=1.25 */
#define LW_G  0.05544842f  /* |d|=2.25 */
#define LW_H -0.01505400f  /* |d|=3.25 */

// ---------------- kernel 0: init min/max key slots (ws is poisoned) ----------
__global__ void k_init(unsigned* __restrict__ maxk, unsigned* __restrict__ mink) {
  int i = threadIdx.x;
  if (i < NB) maxk[i] = 0u;
  else if (i < 2 * NB) mink[i - NB] = 0xFFFFFFFFu;
}

// ---------------- direct-load tile resampler (no LDS, no barriers) -----------
// Thread task: col-octet o = tid&15 (out cols ow0+8o..+7), row-pair p = tid>>4
// (out rows oh0+2p, 2p+1). The 9-row x 3-quad tap neighborhood is read straight
// from global: per-channel input is 1 MB (L2/L3-resident) and a wave's 64
// lanes' taps overlap almost entirely, so caches provide the reuse that LDS
// staging provided -- without the stage+barrier serialization or conflicts.
// Border semantics: row index clamped; the only column-OOB quads are quad -1
// (x-block 0, o==0, g==0: cols -4..-1 -> all replicate col 0) and quad 128
// (x-block 7, o==15, g==2: cols 512..515 -> all replicate col 511), fixed up
// with an edge-scalar splat. Exact replicate border.
__device__ __forceinline__ void lanczos_tile(
    const float* __restrict__ xchan, int oh0, int ow0, int o, int p,
    float pr2[2][8]) {
  const int row0 = (oh0 >> 1) - 4;
  const int qb = ((ow0 >> 1) - 4) >> 2;   // quad base (can be -1); (64k-4)/4 exact

  const float w0[8] = {LW_A, LW_B, LW_C, LW_D, LW_E, LW_F, LW_G, LW_H};
  const float w1[8] = {LW_H, LW_G, LW_F, LW_E, LW_D, LW_C, LW_B, LW_A};

  float ve[12], vo[12];
#pragma unroll
  for (int c = 0; c < 12; ++c) { ve[c] = 0.f; vo[c] = 0.f; }

#pragma unroll
  for (int j = 0; j < 9; ++j) {
    int gr = row0 + p + j;
    gr = gr < 0 ? 0 : (gr > IN_HW - 1 ? IN_HW - 1 : gr);
    const float* __restrict__ rowp = xchan + ((size_t)gr << 9);
#pragma unroll
    for (int g = 0; g < 3; ++g) {
      const int q = qb + o + g;
      const int qc = q < 0 ? 0 : (q > IN_HW / 4 - 1 ? IN_HW / 4 - 1 : q);
      float4 t = reinterpret_cast<const float4*>(rowp)[qc];
      if (q < 0)            { float e = rowp[0];         t = make_float4(e, e, e, e); }
      if (q > IN_HW / 4 - 1){ float e = rowp[IN_HW - 1]; t = make_float4(e, e, e, e); }
      const float tv[4] = {t.x, t.y, t.z, t.w};
#pragma unroll
      for (int c = 0; c < 4; ++c) {
        if (j < 8) ve[4 * g + c] = fmaf(w0[j], tv[c], ve[4 * g + c]);
        if (j > 0) vo[4 * g + c] = fmaf(w1[j - 1], tv[c], vo[4 * g + c]);
      }
    }
  }

  // horizontal: even out col 8o+2m taps v[m..m+7] (w0); odd taps v[m+1..m+8] (w1)
#pragma unroll
  for (int row = 0; row < 2; ++row) {
    const float* v = row ? vo : ve;
#pragma unroll
    for (int m = 0; m < 4; ++m) {
      float pe = 0.f, po = 0.f;
#pragma unroll
      for (int j = 0; j < 8; ++j) {
        pe = fmaf(w0[j], v[m + j], pe);
        po = fmaf(w1[j], v[m + 1 + j], po);
      }
      pr2[row][2 * m] = pe; pr2[row][2 * m + 1] = po;
    }
  }
}

// ---------------- kernel 1: resize (registers only) + per-image min/max ------
__global__ __launch_bounds__(NTHREADS) void k_minmax(
    const float* __restrict__ x,
    unsigned* __restrict__ maxk, unsigned* __restrict__ mink) {
  __shared__ float wred[8];
  const int tid = threadIdx.x;
  const int bc = blockIdx.z;
  const float* __restrict__ xchan = x + (size_t)bc * (IN_HW * IN_HW);
  float pr2[2][8];
  lanczos_tile(xchan, blockIdx.y * TOH, blockIdx.x * TOW, tid & 15, tid >> 4, pr2);

  float mx = pr2[0][0], mn = pr2[0][0];
#pragma unroll
  for (int r = 0; r < 2; ++r)
#pragma unroll
    for (int i = 0; i < 8; ++i) {
      mx = fmaxf(mx, pr2[r][i]); mn = fminf(mn, pr2[r][i]);
    }
#pragma unroll
  for (int s = 32; s > 0; s >>= 1) {
    mx = fmaxf(mx, __shfl_xor(mx, s, 64));
    mn = fminf(mn, __shfl_xor(mn, s, 64));
  }
  if ((tid & 63) == 0) { wred[tid >> 6] = mx; wred[4 + (tid >> 6)] = mn; }
  __syncthreads();
  if (tid == 0) {
    float bmx = fmaxf(fmaxf(wred[0], wred[1]), fmaxf(wred[2], wred[3]));
    float bmn = fminf(fminf(wred[4], wred[5]), fminf(wred[6], wred[7]));
    int b = bc / NC;
    atomicMax(&maxk[b], enc_f(bmx));
    atomicMin(&mink[b], enc_f(bmn));
  }
}

// ---------------- kernel 2: recompute resize + renorm + saturating store -----
__device__ __forceinline__ int renorm1(float img, bool applies, float cA, float cB,
                                       float om_ott, float om_ubt) {
  const float ott = 1.0f / 255.0f;
  const float ubt = -10.0f / 255.0f;
  float v1 = (img > 1.0f) ? fmaf(img - 1.0f, cA, 1.0f - ott)
           : (img < 1.0f) ? img * om_ott : img;
  float v2 = (v1 < 0.0f) ? fmaf(v1, cB, ubt)
           : (v1 > 0.0f) ? v1 * om_ubt : v1;
  float y = (applies ? v2 : img) * 255.0f;
  int t = (int)y;                       // XLA f32->u8: trunc toward zero
  return t < 0 ? 0 : (t > 255 ? 255 : t);
}

__global__ __launch_bounds__(NTHREADS) void k_final(
    const float* __restrict__ x,
    const unsigned* __restrict__ maxk, const unsigned* __restrict__ mink,
    int* __restrict__ out) {
  const int tid = threadIdx.x;
  const int bc = blockIdx.z;
  const int b = bc / NC;
  const float mx = dec_f(maxk[b]);
  const float mn = dec_f(mink[b]);
  const bool applies = (mx - mn) > 1.0f;
  const float ott = 1.0f / 255.0f;
  const float ubt = -10.0f / 255.0f;
  const float otr = mx - 1.0f;
  const float cA = ott / ((otr != 0.0f) ? otr : 1.0f);
  const float cB = ubt / ((mn != 0.0f) ? mn : 1.0f);
  const float om_ott = 1.0f - ott;
  const float om_ubt = 1.0f - ubt;

  const int oh0 = blockIdx.y * TOH, ow0 = blockIdx.x * TOW;
  const float* __restrict__ xchan = x + (size_t)bc * (IN_HW * IN_HW);
  const int o = tid & 15;
  const int p = tid >> 4;
  float pr2[2][8];
  lanczos_tile(xchan, oh0, ow0, o, p, pr2);

  const size_t base = (size_t)bc * (OUT_HW * OUT_HW) +
                      (size_t)(oh0 + 2 * p) * OUT_HW + (ow0 + 8 * o);
#pragma unroll
  for (int row = 0; row < 2; ++row) {
    int q[8];
#pragma unroll
    for (int i = 0; i < 8; ++i)
      q[i] = renorm1(pr2[row][i], applies, cA, cB, om_ott, om_ubt);
    int* dst = out + base + (size_t)row * OUT_HW;
    *reinterpret_cast<int4*>(dst)     = make_int4(q[0], q[1], q[2], q[3]);
    *reinterpret_cast<int4*>(dst + 4) = make_int4(q[4], q[5], q[6], q[7]);
  }
}

extern "C" void kernel_launch(void* const* d_in, const int* in_sizes, int n_in,
                              void* d_out, int out_size, void* d_ws, size_t ws_size,
                              hipStream_t stream) {
  const float* x = (const float*)d_in[0];
  unsigned* maxk = (unsigned*)d_ws;
  unsigned* mink = maxk + NB;

  hipLaunchKernelGGL(k_init, dim3(1), dim3(64), 0, stream, maxk, mink);
  dim3 grid(OUT_HW / TOW, OUT_HW / TOH, NB * NC);
  hipLaunchKernelGGL(k_minmax, grid, dim3(NTHREADS), 0, stream, x, maxk, mink);
  hipLaunchKernelGGL(k_final, grid, dim3(NTHREADS), 0, stream,
                     x, maxk, mink, (int*)d_out);
}

// Round 5
// 774.166 us; speedup vs baseline: 1.1445x; 1.1445x over previous
//
#include <hip/hip_runtime.h>

#define IN_HW 512
#define OUT_HW 1024
#define NB 32
#define NC 3
#define TOH 32
#define TOW 128
#define NTHREADS 256

typedef float  f32x4 __attribute__((ext_vector_type(4)));
typedef int    i32x4 __attribute__((ext_vector_type(4)));

// ---------------- sortable-key encoding for f32 atomics ----------------------
__device__ __forceinline__ unsigned enc_f(float f) {
  unsigned u = __float_as_uint(f);
  return (u & 0x80000000u) ? ~u : (u | 0x80000000u);
}
__device__ __forceinline__ float dec_f(unsigned k) {
  unsigned u = (k & 0x80000000u) ? (k ^ 0x80000000u) : ~k;
  return __uint_as_float(u);
}

// ---------------- hardcoded normalized Lanczos4 2x-upsample weights ----------
// Derived in f64: w(d)=sinc(d)sinc(d/4), phases d=3.75-j (even) / 3.25-j (odd),
// normalized to sum 1. Max abs error ~2e-6 -> output perturbation ~0.05 u8
// levels; cannot change absmax class.
#define LW_A -0.00397053f  /* |d|=3.75 */
#define LW_B  0.03146474f  /* |d|=2.75 */
#define LW_C -0.09165979f  /* |d|=1.75 */
#define LW_D  0.28268104f  /* |d|=0.75 */
#define LW_E  0.89337959f  /* |d|=0.25 */
#define LW_F -0.15228947f  /* |d|=1.25 */
#define LW_G  0.05544842f  /* |d|=2.25 */
#define LW_H -0.01505400f  /* |d|=3.25 */

// ---------------- kernel 0: init min/max key slots (ws is poisoned) ----------
__global__ void k_init(unsigned* __restrict__ maxk, unsigned* __restrict__ mink) {
  int i = threadIdx.x;
  if (i < NB) maxk[i] = 0u;
  else if (i < 2 * NB) mink[i - NB] = 0xFFFFFFFFu;
}

// ---------------- direct-load tile resampler (no LDS, no barriers) -----------
// Thread task: col-octet o = tid&15 (out cols ow0+8o..+7), row-pair p = tid>>4
// (out rows oh0+2p, 2p+1). Taps read straight from global (L1/L2-resident,
// heavy intra-wave overlap). Border: row clamp; column-OOB only quad -1
// (splat col 0) and quad 128 (splat col 511). Exact replicate border.
__device__ __forceinline__ void lanczos_tile(
    const float* __restrict__ xchan, int oh0, int ow0, int o, int p,
    float pr2[2][8]) {
  const int row0 = (oh0 >> 1) - 4;
  const int qb = ((ow0 >> 1) - 4) >> 2;   // quad base (can be -1)

  const float w0[8] = {LW_A, LW_B, LW_C, LW_D, LW_E, LW_F, LW_G, LW_H};
  const float w1[8] = {LW_H, LW_G, LW_F, LW_E, LW_D, LW_C, LW_B, LW_A};

  float ve[12], vo[12];
#pragma unroll
  for (int c = 0; c < 12; ++c) { ve[c] = 0.f; vo[c] = 0.f; }

#pragma unroll
  for (int j = 0; j < 9; ++j) {
    int gr = row0 + p + j;
    gr = gr < 0 ? 0 : (gr > IN_HW - 1 ? IN_HW - 1 : gr);
    const float* __restrict__ rowp = xchan + ((size_t)gr << 9);
#pragma unroll
    for (int g = 0; g < 3; ++g) {
      const int q = qb + o + g;
      const int qc = q < 0 ? 0 : (q > IN_HW / 4 - 1 ? IN_HW / 4 - 1 : q);
      float4 t = reinterpret_cast<const float4*>(rowp)[qc];
      if (q < 0)            { float e = rowp[0];         t = make_float4(e, e, e, e); }
      if (q > IN_HW / 4 - 1){ float e = rowp[IN_HW - 1]; t = make_float4(e, e, e, e); }
      const float tv[4] = {t.x, t.y, t.z, t.w};
#pragma unroll
      for (int c = 0; c < 4; ++c) {
        if (j < 8) ve[4 * g + c] = fmaf(w0[j], tv[c], ve[4 * g + c]);
        if (j > 0) vo[4 * g + c] = fmaf(w1[j - 1], tv[c], vo[4 * g + c]);
      }
    }
  }

  // horizontal: even out col 8o+2m taps v[m..m+7] (w0); odd taps v[m+1..m+8] (w1)
#pragma unroll
  for (int row = 0; row < 2; ++row) {
    const float* v = row ? vo : ve;
#pragma unroll
    for (int m = 0; m < 4; ++m) {
      float pe = 0.f, po = 0.f;
#pragma unroll
      for (int j = 0; j < 8; ++j) {
        pe = fmaf(w0[j], v[m + j], pe);
        po = fmaf(w1[j], v[m + 1 + j], po);
      }
      pr2[row][2 * m] = pe; pr2[row][2 * m + 1] = po;
    }
  }
}

// -------- kernel 1: resize ONCE -> f32 spill to out + per-image min/max ------
__global__ __launch_bounds__(NTHREADS) void k_resize(
    const float* __restrict__ x, float* __restrict__ outf,
    unsigned* __restrict__ maxk, unsigned* __restrict__ mink) {
  __shared__ float wred[8];
  const int tid = threadIdx.x;
  const int bc = blockIdx.z;
  const int oh0 = blockIdx.y * TOH, ow0 = blockIdx.x * TOW;
  const float* __restrict__ xchan = x + (size_t)bc * (IN_HW * IN_HW);
  const int o = tid & 15;
  const int p = tid >> 4;
  float pr2[2][8];
  lanczos_tile(xchan, oh0, ow0, o, p, pr2);

  // spill f32 bits into the int32-per-pixel output buffer (pass 2 converts)
  const size_t base = (size_t)bc * (OUT_HW * OUT_HW) +
                      (size_t)(oh0 + 2 * p) * OUT_HW + (ow0 + 8 * o);
#pragma unroll
  for (int row = 0; row < 2; ++row) {
    float* dst = outf + base + (size_t)row * OUT_HW;
    *reinterpret_cast<float4*>(dst)     = make_float4(pr2[row][0], pr2[row][1],
                                                      pr2[row][2], pr2[row][3]);
    *reinterpret_cast<float4*>(dst + 4) = make_float4(pr2[row][4], pr2[row][5],
                                                      pr2[row][6], pr2[row][7]);
  }

  float mx = pr2[0][0], mn = pr2[0][0];
#pragma unroll
  for (int r = 0; r < 2; ++r)
#pragma unroll
    for (int i = 0; i < 8; ++i) {
      mx = fmaxf(mx, pr2[r][i]); mn = fminf(mn, pr2[r][i]);
    }
#pragma unroll
  for (int s = 32; s > 0; s >>= 1) {
    mx = fmaxf(mx, __shfl_xor(mx, s, 64));
    mn = fminf(mn, __shfl_xor(mn, s, 64));
  }
  if ((tid & 63) == 0) { wred[tid >> 6] = mx; wred[4 + (tid >> 6)] = mn; }
  __syncthreads();
  if (tid == 0) {
    float bmx = fmaxf(fmaxf(wred[0], wred[1]), fmaxf(wred[2], wred[3]));
    float bmn = fminf(fminf(wred[4], wred[5]), fminf(wred[6], wred[7]));
    int b = bc / NC;
    atomicMax(&maxk[b], enc_f(bmx));
    atomicMin(&mink[b], enc_f(bmn));
  }
}

// ---------------- kernel 2: in-place renorm f32 -> saturating int32 ----------
// Pure stream, zero reuse: nontemporal load/store so the 768 MB RMW doesn't
// churn L2/L3. One float4 per thread.
__device__ __forceinline__ int renorm1(float img, bool applies, float cA, float cB,
                                       float om_ott, float om_ubt) {
  const float ott = 1.0f / 255.0f;
  const float ubt = -10.0f / 255.0f;
  float v1 = (img > 1.0f) ? fmaf(img - 1.0f, cA, 1.0f - ott)
           : (img < 1.0f) ? img * om_ott : img;
  float v2 = (v1 < 0.0f) ? fmaf(v1, cB, ubt)
           : (v1 > 0.0f) ? v1 * om_ubt : v1;
  float y = (applies ? v2 : img) * 255.0f;
  int t = (int)y;                       // XLA f32->u8: trunc toward zero
  return t < 0 ? 0 : (t > 255 ? 255 : t);
}

#define N4_PER_IMG (NC * OUT_HW * OUT_HW / 4)   // 786432 float4 per image

__global__ __launch_bounds__(NTHREADS) void k_renorm(
    int* out, const unsigned* __restrict__ maxk, const unsigned* __restrict__ mink) {
  const int b = blockIdx.y;
  const float mx = dec_f(maxk[b]);
  const float mn = dec_f(mink[b]);
  const bool applies = (mx - mn) > 1.0f;
  const float ott = 1.0f / 255.0f;
  const float ubt = -10.0f / 255.0f;
  const float otr = mx - 1.0f;
  const float cA = ott / ((otr != 0.0f) ? otr : 1.0f);
  const float cB = ubt / ((mn != 0.0f) ? mn : 1.0f);
  const float om_ott = 1.0f - ott;
  const float om_ubt = 1.0f - ubt;

  const size_t idx = (size_t)b * N4_PER_IMG +
                     (size_t)blockIdx.x * NTHREADS + threadIdx.x;
  const f32x4 v = __builtin_nontemporal_load(
      reinterpret_cast<const f32x4*>(out) + idx);
  i32x4 r;
  r.x = renorm1(v.x, applies, cA, cB, om_ott, om_ubt);
  r.y = renorm1(v.y, applies, cA, cB, om_ott, om_ubt);
  r.z = renorm1(v.z, applies, cA, cB, om_ott, om_ubt);
  r.w = renorm1(v.w, applies, cA, cB, om_ott, om_ubt);
  __builtin_nontemporal_store(r, reinterpret_cast<i32x4*>(out) + idx);
}

extern "C" void kernel_launch(void* const* d_in, const int* in_sizes, int n_in,
                              void* d_out, int out_size, void* d_ws, size_t ws_size,
                              hipStream_t stream) {
  const float* x = (const float*)d_in[0];
  unsigned* maxk = (unsigned*)d_ws;
  unsigned* mink = maxk + NB;

  hipLaunchKernelGGL(k_init, dim3(1), dim3(64), 0, stream, maxk, mink);
  dim3 grid(OUT_HW / TOW, OUT_HW / TOH, NB * NC);
  hipLaunchKernelGGL(k_resize, grid, dim3(NTHREADS), 0, stream,
                     x, (float*)d_out, maxk, mink);
  hipLaunchKernelGGL(k_renorm, dim3(N4_PER_IMG / NTHREADS, NB), dim3(NTHREADS),
                     0, stream, (int*)d_out, maxk, mink);
}